// Round 3
// baseline (3862.407 us; speedup 1.0000x reference)
//
#include <hip/hip_runtime.h>

// 2-layer LSTM (H=50) + FC head. MFMA fp16, occupancy-optimized.
// B=4096, T=512. Grid = 1024 blocks x 256 threads; NB=4 batch/block ->
// 4 blocks/CU (16 waves/CU) so independent blocks' phases interleave and
// hide the per-block barrier-serialized MFMA->elementwise chain.
// Gate rows are PERMUTED p = 4*j + g so each elementwise thread reads its
// 4 gates as a single ds_read_b128.

#define HID 50
#define SEQ 512
#define NB 4
#define NTHREADS 256
#define GP 260            // gates row stride (floats), multiple of 4
#define XP 516            // xs row stride (floats)

typedef _Float16 f16x8 __attribute__((ext_vector_type(8)));
typedef float    f32x4 __attribute__((ext_vector_type(4)));

__device__ __forceinline__ float sigf(float x) {
    return 1.0f / (1.0f + __expf(-x));
}
__device__ __forceinline__ float tanh_fast(float x) {
    return 2.0f / (1.0f + __expf(-2.0f * x)) - 1.0f;  // saturates correctly
}

// h-buffer chunk index: [kt][q][m^(q+4kt)] of 16B (8 half) chunks.
// Reader (A-frag, lane m=l15, quad qq): chunk = kt*64 + qq*16 + (m ^ (qq+4kt))
//   -> 64 lanes read 64 distinct contiguous chunks: conflict-free ds_read_b128.
// Writer (unit j, batch b): kt=j>>5, qh=(j>>3)&3, e=j&7.
__device__ __forceinline__ int hchunk(int kt, int qh, int b) {
    return kt * 64 + qh * 16 + (b ^ (qh + 4 * kt));
}

__global__ __launch_bounds__(NTHREADS, 4)
void lstm2_fc_mfma(const float* __restrict__ x,
                   const float* __restrict__ w_ih0,
                   const float* __restrict__ w_hh0,
                   const float* __restrict__ b_ih0,
                   const float* __restrict__ b_hh0,
                   const float* __restrict__ w_ih1,
                   const float* __restrict__ w_hh1,
                   const float* __restrict__ b_ih1,
                   const float* __restrict__ b_hh1,
                   const float* __restrict__ fc_w,
                   const float* __restrict__ fc_b,
                   float* __restrict__ out)
{
    __shared__ float xs[NB * XP];        //  8.3 KB  x for all 512 steps
    __shared__ float gates[NB * GP];     //  4.2 KB  C-layout gate preacts (permuted cols)
    __shared__ f16x8 h1f[128];           //  2 KB    h1 in A-frag layout (16 rows, 4 used)
    __shared__ f16x8 h2f[128];           //  2 KB    h2 in A-frag layout

    const int tid = threadIdx.x;
    const int b0  = blockIdx.x * NB;
    const int w   = tid >> 6;            // wave id 0..3
    const int l15 = tid & 15;            // MFMA lane column
    const int qq  = (tid >> 4) & 3;      // MFMA lane quad

    // ---- stage x into LDS (coalesced float4) ----
    for (int idx = tid; idx < NB * 128; idx += NTHREADS) {
        const int b  = idx >> 7;
        const int t4 = idx & 127;
        *(float4*)&xs[b * XP + t4 * 4] =
            *(const float4*)&x[(size_t)(b0 + b) * SEQ + t4 * 4];
    }
    // ---- zero h buffers (rows 4..15 must stay zero forever) ----
    if (tid < 128) { f16x8 z = {}; h1f[tid] = z; }
    else           { f16x8 z = {}; h2f[tid - 128] = z; }

    // ---- load weight B-fragments (one-time), with gate-row permutation ----
    // Column position p = T*16 + l15 holds source gate-row n = (p&3)*HID + (p>>2),
    // so elementwise unit j's 4 gates are columns 4j..4j+3.
    const float* mats[3] = { w_hh0, w_ih1, w_hh1 };
    f16x8 wf[3][4][2];
    float wx0t[4], bAt[4], bBt[4];
#pragma unroll
    for (int i = 0; i < 4; ++i) {
        const int  T   = w * 4 + i;          // 16 N-tiles over 4 waves
        const int  p   = T * 16 + l15;
        const bool pok = (p < 4 * HID);
        const int  n   = pok ? ((p & 3) * HID + (p >> 2)) : 0;
        wx0t[i] = pok ? w_ih0[n] : 0.0f;
        bAt[i]  = pok ? (b_ih0[n] + b_hh0[n]) : 0.0f;
        bBt[i]  = pok ? (b_ih1[n] + b_hh1[n]) : 0.0f;
#pragma unroll
        for (int mi = 0; mi < 3; ++mi) {
#pragma unroll
            for (int kt = 0; kt < 2; ++kt) {
                f16x8 f;
#pragma unroll
                for (int j = 0; j < 8; ++j) {
                    const int k = kt * 32 + qq * 8 + j;
                    const float v = (pok && k < HID) ? mats[mi][n * HID + k] : 0.0f;
                    f[j] = (_Float16)v;
                }
                wf[mi][i][kt] = f;
            }
        }
    }

    // ---- elementwise mapping: unit j = tid&63 (j<50), batch = wave id ----
    const int  jslot  = tid & 63;
    const bool active = (jslot < HID);
    const int  jj     = active ? jslot : 0;
    const int  eb     = w;                   // one batch per wave
    const int  ekt    = jj >> 5;
    const int  eqh    = (jj >> 3) & 3;
    const int  ee     = jj & 7;
    _Float16*  h1e    = (_Float16*)h1f;
    _Float16*  h2e    = (_Float16*)h2f;

    float c1 = 0.f, c2 = 0.f;

    __syncthreads();   // xs, h zeros visible

    for (int t = 0; t < SEQ; ++t) {
        // ============ Phase A: L1 MFMA  gates = h1 @ w_hh0^T + x*wx + bA ====
        {
            const f16x8 a0 = h1f[qq * 16 + (l15 ^ qq)];
            const f16x8 a1 = h1f[64 + qq * 16 + (l15 ^ (qq + 4))];
            float xv[4];
#pragma unroll
            for (int r = 0; r < 4; ++r)
                xv[r] = (qq == 0) ? xs[r * XP + t] : 0.0f;   // rows m=qq*4+r, only m<4 real
#pragma unroll
            for (int i = 0; i < 4; ++i) {
                f32x4 acc;
#pragma unroll
                for (int r = 0; r < 4; ++r) acc[r] = xv[r] * wx0t[i] + bAt[i];
                acc = __builtin_amdgcn_mfma_f32_16x16x32_f16(a0, wf[0][i][0], acc, 0, 0, 0);
                acc = __builtin_amdgcn_mfma_f32_16x16x32_f16(a1, wf[0][i][1], acc, 0, 0, 0);
                if (qq == 0) {                                // rows 0..3 are the batch
                    const int base = (w * 4 + i) * 16 + l15;
#pragma unroll
                    for (int r = 0; r < 4; ++r) gates[r * GP + base] = acc[r];
                }
            }
        }
        __syncthreads();

        // ============ Phase B: L1 elementwise -> h1f ============
        if (active) {
            const float4 g4 = *(const float4*)&gates[eb * GP + 4 * jj];
            const float ii = sigf(g4.x);
            const float ff = sigf(g4.y);
            const float g2 = tanh_fast(g4.z);
            const float oo = sigf(g4.w);
            c1 = ff * c1 + ii * g2;
            const float h = oo * tanh_fast(c1);
            h1e[hchunk(ekt, eqh, eb) * 8 + ee] = (_Float16)h;
        }
        __syncthreads();

        // ============ Phase C: L2 MFMA  gates = h1@w_ih1^T + h2@w_hh1^T + bB
        {
            const f16x8 p0 = h1f[qq * 16 + (l15 ^ qq)];
            const f16x8 p1 = h1f[64 + qq * 16 + (l15 ^ (qq + 4))];
            const f16x8 s0 = h2f[qq * 16 + (l15 ^ qq)];
            const f16x8 s1 = h2f[64 + qq * 16 + (l15 ^ (qq + 4))];
#pragma unroll
            for (int i = 0; i < 4; ++i) {
                f32x4 acc;
#pragma unroll
                for (int r = 0; r < 4; ++r) acc[r] = bBt[i];
                acc = __builtin_amdgcn_mfma_f32_16x16x32_f16(p0, wf[1][i][0], acc, 0, 0, 0);
                acc = __builtin_amdgcn_mfma_f32_16x16x32_f16(p1, wf[1][i][1], acc, 0, 0, 0);
                acc = __builtin_amdgcn_mfma_f32_16x16x32_f16(s0, wf[2][i][0], acc, 0, 0, 0);
                acc = __builtin_amdgcn_mfma_f32_16x16x32_f16(s1, wf[2][i][1], acc, 0, 0, 0);
                if (qq == 0) {
                    const int base = (w * 4 + i) * 16 + l15;
#pragma unroll
                    for (int r = 0; r < 4; ++r) gates[r * GP + base] = acc[r];
                }
            }
        }
        __syncthreads();

        // ============ Phase D: L2 elementwise -> h2f ============
        if (active) {
            const float4 g4 = *(const float4*)&gates[eb * GP + 4 * jj];
            const float ii = sigf(g4.x);
            const float ff = sigf(g4.y);
            const float g2 = tanh_fast(g4.z);
            const float oo = sigf(g4.w);
            c2 = ff * c2 + ii * g2;
            const float h = oo * tanh_fast(c2);
            h2e[hchunk(ekt, eqh, eb) * 8 + ee] = (_Float16)h;
        }
        __syncthreads();
    }

    // ============ FC head: out[b] = h2[T-1] . fc_w + fc_b ============
    if (tid < NB) {
        const int b = tid;
        float s = fc_b[0];
        for (int j = 0; j < HID; ++j) {
            const int kt = j >> 5, qh = (j >> 3) & 3, e = j & 7;
            s += fc_w[j] * (float)h2e[hchunk(kt, qh, b) * 8 + e];
        }
        out[b0 + b] = s;
    }
}

extern "C" void kernel_launch(void* const* d_in, const int* in_sizes, int n_in,
                              void* d_out, int out_size, void* d_ws, size_t ws_size,
                              hipStream_t stream) {
    const float* x     = (const float*)d_in[0];
    const float* w_ih0 = (const float*)d_in[1];
    const float* w_hh0 = (const float*)d_in[2];
    const float* b_ih0 = (const float*)d_in[3];
    const float* b_hh0 = (const float*)d_in[4];
    const float* w_ih1 = (const float*)d_in[5];
    const float* w_hh1 = (const float*)d_in[6];
    const float* b_ih1 = (const float*)d_in[7];
    const float* b_hh1 = (const float*)d_in[8];
    const float* fc_w  = (const float*)d_in[9];
    const float* fc_b  = (const float*)d_in[10];
    float* out = (float*)d_out;

    const int B = in_sizes[0] / SEQ;  // 4096

    lstm2_fc_mfma<<<B / NB, NTHREADS, 0, stream>>>(
        x, w_ih0, w_hh0, b_ih0, b_hh0, w_ih1, w_hh1, b_ih1, b_hh1, fc_w, fc_b, out);
}

// Round 4
// 1102.664 us; speedup vs baseline: 3.5028x; 3.5028x over previous
//
#include <hip/hip_runtime.h>

// 2-layer LSTM (H=50) + FC head. MFMA fp16.
// B=4096, T=512. Grid = 512 blocks x 512 threads (8 waves); NB=8 batch/block.
// __launch_bounds__(512,4) -> 2 blocks/CU (16 waves/CU): two independent
// phase-streams per CU hide the barrier-serialized MFMA->elementwise chain.
// Weight B-fragments: 2 N-tiles/wave -> 12 frags = 48 VGPR (R3's 24-frag
// version spilled under a 4-waves/EU budget -> 13 GB scratch traffic).
// Gate rows PERMUTED p = 4*j + g so elementwise reads one float4 per thread.

#define HID 50
#define SEQ 512
#define NB 8
#define NTHREADS 512
#define GP 260            // gates row stride (floats)
#define XP 516            // xs row stride (floats)

typedef _Float16 f16x8 __attribute__((ext_vector_type(8)));
typedef float    f32x4 __attribute__((ext_vector_type(4)));

__device__ __forceinline__ float sigf(float x) {
    return 1.0f / (1.0f + __expf(-x));
}
__device__ __forceinline__ float tanh_fast(float x) {
    return 2.0f / (1.0f + __expf(-2.0f * x)) - 1.0f;  // saturates correctly
}

// h-buffer chunk index: [kt][q][m^(q+4kt)] of 16B (8 half) chunks.
// Reader (A-frag, lane m=l15, quad qq): chunk = kt*64 + qq*16 + (m ^ (qq+4kt))
//   -> 64 lanes read 64 distinct contiguous 16B chunks: conflict-free b128.
// Writer (unit j, batch b): kt=j>>5, qh=(j>>3)&3, e=j&7.
__device__ __forceinline__ int hchunk(int kt, int qh, int b) {
    return kt * 64 + qh * 16 + (b ^ (qh + 4 * kt));
}

__global__ __launch_bounds__(NTHREADS, 4)
void lstm2_fc_mfma(const float* __restrict__ x,
                   const float* __restrict__ w_ih0,
                   const float* __restrict__ w_hh0,
                   const float* __restrict__ b_ih0,
                   const float* __restrict__ b_hh0,
                   const float* __restrict__ w_ih1,
                   const float* __restrict__ w_hh1,
                   const float* __restrict__ b_ih1,
                   const float* __restrict__ b_hh1,
                   const float* __restrict__ fc_w,
                   const float* __restrict__ fc_b,
                   float* __restrict__ out)
{
    __shared__ float xs[NB * XP];        // 16.5 KB  x for all 512 steps
    __shared__ float gates[NB * GP];     //  8.3 KB  permuted gate preacts
    __shared__ f16x8 h1f[128];           //  2 KB    h1 in A-frag layout
    __shared__ f16x8 h2f[128];           //  2 KB    h2 in A-frag layout

    const int tid = threadIdx.x;
    const int b0  = blockIdx.x * NB;
    const int w   = tid >> 6;            // wave id 0..7
    const int l15 = tid & 15;            // MFMA lane column
    const int qq  = (tid >> 4) & 3;      // MFMA lane quad

    // ---- stage x into LDS (coalesced float4) ----
    for (int idx = tid; idx < NB * 128; idx += NTHREADS) {
        const int b  = idx >> 7;
        const int t4 = idx & 127;
        *(float4*)&xs[b * XP + t4 * 4] =
            *(const float4*)&x[(size_t)(b0 + b) * SEQ + t4 * 4];
    }
    // ---- zero h buffers (rows NB..15 must stay zero forever) ----
    if (tid < 128)      { f16x8 z = {}; h1f[tid] = z; }
    else if (tid < 256) { f16x8 z = {}; h2f[tid - 128] = z; }

    // ---- load weight B-fragments (one-time), with gate-row permutation ----
    // Column position p holds source gate-row n = (p&3)*HID + (p>>2),
    // so elementwise unit j's 4 gates are columns 4j..4j+3.
    const float* mats[3] = { w_hh0, w_ih1, w_hh1 };
    f16x8 wf[3][2][2];                   // [mat][tile][kt] = 12 frags = 48 VGPR
    float wx0t[2], bAt[2], bBt[2];
#pragma unroll
    for (int i = 0; i < 2; ++i) {
        const int  T   = w * 2 + i;          // 16 N-tiles over 8 waves
        const int  p   = T * 16 + l15;
        const bool pok = (p < 4 * HID);
        const int  n   = pok ? ((p & 3) * HID + (p >> 2)) : 0;
        wx0t[i] = pok ? w_ih0[n] : 0.0f;
        bAt[i]  = pok ? (b_ih0[n] + b_hh0[n]) : 0.0f;
        bBt[i]  = pok ? (b_ih1[n] + b_hh1[n]) : 0.0f;
#pragma unroll
        for (int mi = 0; mi < 3; ++mi) {
#pragma unroll
            for (int kt = 0; kt < 2; ++kt) {
                f16x8 f;
#pragma unroll
                for (int j = 0; j < 8; ++j) {
                    const int k = kt * 32 + qq * 8 + j;
                    const float v = (pok && k < HID) ? mats[mi][n * HID + k] : 0.0f;
                    f[j] = (_Float16)v;
                }
                wf[mi][i][kt] = f;
            }
        }
    }

    // ---- elementwise mapping: unit j = tid&63 (j<50), batch = wave id ----
    const int  jslot  = tid & 63;
    const bool active = (jslot < HID);
    const int  jj     = active ? jslot : 0;
    const int  eb     = w;                   // one batch per wave
    const int  ekt    = jj >> 5;
    const int  eqh    = (jj >> 3) & 3;
    const int  ee     = jj & 7;
    _Float16*  h1e    = (_Float16*)h1f;
    _Float16*  h2e    = (_Float16*)h2f;

    float c1 = 0.f, c2 = 0.f;

    __syncthreads();   // xs, h zeros visible

    for (int t = 0; t < SEQ; ++t) {
        // ============ Phase A: L1 MFMA  gates = h1 @ w_hh0^T + x*wx + bA ====
        {
            const f16x8 a0 = h1f[qq * 16 + (l15 ^ qq)];
            const f16x8 a1 = h1f[64 + qq * 16 + (l15 ^ (qq + 4))];
            float xv[4];
#pragma unroll
            for (int r = 0; r < 4; ++r)
                xv[r] = (qq < 2) ? xs[(qq * 4 + r) * XP + t] : 0.0f;  // rows m<8 real
#pragma unroll
            for (int i = 0; i < 2; ++i) {
                f32x4 acc;
#pragma unroll
                for (int r = 0; r < 4; ++r) acc[r] = xv[r] * wx0t[i] + bAt[i];
                acc = __builtin_amdgcn_mfma_f32_16x16x32_f16(a0, wf[0][i][0], acc, 0, 0, 0);
                acc = __builtin_amdgcn_mfma_f32_16x16x32_f16(a1, wf[0][i][1], acc, 0, 0, 0);
                if (qq < 2) {                                 // rows 0..7 = batch
                    const int base = (w * 2 + i) * 16 + l15;
#pragma unroll
                    for (int r = 0; r < 4; ++r) gates[(qq * 4 + r) * GP + base] = acc[r];
                }
            }
        }
        __syncthreads();

        // ============ Phase B: L1 elementwise -> h1f ============
        if (active) {
            const float4 g4 = *(const float4*)&gates[eb * GP + 4 * jj];
            const float ii = sigf(g4.x);
            const float ff = sigf(g4.y);
            const float g2 = tanh_fast(g4.z);
            const float oo = sigf(g4.w);
            c1 = ff * c1 + ii * g2;
            const float h = oo * tanh_fast(c1);
            h1e[hchunk(ekt, eqh, eb) * 8 + ee] = (_Float16)h;
        }
        __syncthreads();

        // ============ Phase C: L2 MFMA  gates = h1@w_ih1^T + h2@w_hh1^T + bB
        {
            const f16x8 p0 = h1f[qq * 16 + (l15 ^ qq)];
            const f16x8 p1 = h1f[64 + qq * 16 + (l15 ^ (qq + 4))];
            const f16x8 s0 = h2f[qq * 16 + (l15 ^ qq)];
            const f16x8 s1 = h2f[64 + qq * 16 + (l15 ^ (qq + 4))];
#pragma unroll
            for (int i = 0; i < 2; ++i) {
                f32x4 acc;
#pragma unroll
                for (int r = 0; r < 4; ++r) acc[r] = bBt[i];
                acc = __builtin_amdgcn_mfma_f32_16x16x32_f16(p0, wf[1][i][0], acc, 0, 0, 0);
                acc = __builtin_amdgcn_mfma_f32_16x16x32_f16(p1, wf[1][i][1], acc, 0, 0, 0);
                acc = __builtin_amdgcn_mfma_f32_16x16x32_f16(s0, wf[2][i][0], acc, 0, 0, 0);
                acc = __builtin_amdgcn_mfma_f32_16x16x32_f16(s1, wf[2][i][1], acc, 0, 0, 0);
                if (qq < 2) {
                    const int base = (w * 2 + i) * 16 + l15;
#pragma unroll
                    for (int r = 0; r < 4; ++r) gates[(qq * 4 + r) * GP + base] = acc[r];
                }
            }
        }
        __syncthreads();

        // ============ Phase D: L2 elementwise -> h2f ============
        if (active) {
            const float4 g4 = *(const float4*)&gates[eb * GP + 4 * jj];
            const float ii = sigf(g4.x);
            const float ff = sigf(g4.y);
            const float g2 = tanh_fast(g4.z);
            const float oo = sigf(g4.w);
            c2 = ff * c2 + ii * g2;
            const float h = oo * tanh_fast(c2);
            h2e[hchunk(ekt, eqh, eb) * 8 + ee] = (_Float16)h;
        }
        __syncthreads();
    }

    // ============ FC head: out[b] = h2[T-1] . fc_w + fc_b ============
    if (tid < NB) {
        const int b = tid;
        float s = fc_b[0];
        for (int j = 0; j < HID; ++j) {
            const int kt = j >> 5, qh = (j >> 3) & 3, e = j & 7;
            s += fc_w[j] * (float)h2e[hchunk(kt, qh, b) * 8 + e];
        }
        out[b0 + b] = s;
    }
}

extern "C" void kernel_launch(void* const* d_in, const int* in_sizes, int n_in,
                              void* d_out, int out_size, void* d_ws, size_t ws_size,
                              hipStream_t stream) {
    const float* x     = (const float*)d_in[0];
    const float* w_ih0 = (const float*)d_in[1];
    const float* w_hh0 = (const float*)d_in[2];
    const float* b_ih0 = (const float*)d_in[3];
    const float* b_hh0 = (const float*)d_in[4];
    const float* w_ih1 = (const float*)d_in[5];
    const float* w_hh1 = (const float*)d_in[6];
    const float* b_ih1 = (const float*)d_in[7];
    const float* b_hh1 = (const float*)d_in[8];
    const float* fc_w  = (const float*)d_in[9];
    const float* fc_b  = (const float*)d_in[10];
    float* out = (float*)d_out;

    const int B = in_sizes[0] / SEQ;  // 4096

    lstm2_fc_mfma<<<B / NB, NTHREADS, 0, stream>>>(
        x, w_ih0, w_hh0, b_ih0, b_hh0, w_ih1, w_hh1, b_ih1, b_hh1, fc_w, fc_b, out);
}

// Round 5
// 872.035 us; speedup vs baseline: 4.4292x; 1.2645x over previous
//
#include <hip/hip_runtime.h>

// 2-layer LSTM (H=50) + FC head. Transposed-MFMA fp16 formulation.
// gates^T[200][16] = W[200][50] @ h^T[50][16]: A-operand = weights (register-
// resident), B-operand = h (LDS, fragment layout). With gate rows permuted
// p = 4*j + g, C/D layout (row=quad*4+reg, col=lane&15) gives ONE LANE all
// four gates of unit j = T*4+qq for batch m = lane&15 -> the LSTM cell update
// is fully in-register: no gates LDS round-trip, 2 barriers/step (was 4).
// B=4096, T=512. Grid = 256 blocks x 512 threads; NB=16 batch/block,
// 13 p-tiles over 8 waves (waves 0-4 own 2 tiles, 5-7 own 1).

#define HID 50
#define SEQ 512
#define NB 16
#define NTHREADS 512
#define XP 516            // xs row stride (floats)

typedef _Float16 f16x8 __attribute__((ext_vector_type(8)));
typedef float    f32x4 __attribute__((ext_vector_type(4)));

__device__ __forceinline__ float sigf(float x) {
    return 1.0f / (1.0f + __expf(-x));
}
__device__ __forceinline__ float tanh_fast(float x) {
    return 2.0f / (1.0f + __expf(-2.0f * x)) - 1.0f;  // saturates correctly
}
__device__ __forceinline__ float lstm_cell(const f32x4 g, float& c) {
    const float ii = sigf(g[0]);
    const float ff = sigf(g[1]);
    const float gg = tanh_fast(g[2]);
    const float oo = sigf(g[3]);
    c = ff * c + ii * gg;
    return oo * tanh_fast(c);
}

// h LDS layout: 16B chunks indexed (kt*4+qq)*16 + m; chunk holds
// h[m][k = kt*32 + qq*8 + 0..7] as 8 halves. B-frag reader (lane m=l15,
// quad qq) reads chunk (kt*4+qq)*16 + m: 64 distinct chunks, conflict-free.

__global__ __launch_bounds__(NTHREADS, 2)
void lstm2_fc_tmfma(const float* __restrict__ x,
                    const float* __restrict__ w_ih0,
                    const float* __restrict__ w_hh0,
                    const float* __restrict__ b_ih0,
                    const float* __restrict__ b_hh0,
                    const float* __restrict__ w_ih1,
                    const float* __restrict__ w_hh1,
                    const float* __restrict__ b_ih1,
                    const float* __restrict__ b_hh1,
                    const float* __restrict__ fc_w,
                    const float* __restrict__ fc_b,
                    float* __restrict__ out)
{
    __shared__ float xs[NB * XP];        // 33 KB  x for all 512 steps
    __shared__ f16x8 h1f[2][128];        //  4 KB  h1 double-buffered, frag layout
    __shared__ f16x8 h2f[2][128];        //  4 KB  h2 double-buffered

    const int tid = threadIdx.x;
    const int b0  = blockIdx.x * NB;
    const int w   = tid >> 6;            // wave id 0..7
    const int l15 = tid & 15;            // MFMA lane column (batch m / A-row)
    const int qq  = (tid >> 4) & 3;      // MFMA lane quad

    // ---- stage x into LDS (coalesced float4) ----
    for (int idx = tid; idx < NB * 128; idx += NTHREADS) {
        const int b  = idx >> 7;
        const int t4 = idx & 127;
        *(float4*)&xs[b * XP + t4 * 4] =
            *(const float4*)&x[(size_t)(b0 + b) * SEQ + t4 * 4];
    }
    // ---- zero h buffers (padding halves j=52..63 must stay zero forever) ----
    if (tid < 256) {
        f16x8 z = {};
        h1f[tid >> 7][tid & 127] = z;
        h2f[tid >> 7][tid & 127] = z;
    }

    // ---- tiles owned by this wave ----
    const int nt = (w < 5) ? 2 : 1;
    const int Ts[2] = { w, 8 + w };

    // ---- load weight A-fragments (one-time), gate rows permuted ----
    // A-frag: lane holds W[p = T*16 + l15][k = kt*32 + qq*8 + j], source gate
    // row n(p) = (p&3)*HID + (p>>2). Zero outside p<200 / k<50.
    const float* mats[3] = { w_hh0, w_ih1, w_hh1 };
    f16x8 wa[3][2][2];                   // [mat][tile][kt] = 12 frags = 48 VGPR
    float wxC[2][4], bAC[2][4], bBC[2][4];
#pragma unroll
    for (int tt = 0; tt < 2; ++tt) {
        const int  T   = Ts[tt];
        const int  p   = T * 16 + l15;
        const bool pok = (tt < nt) && (p < 4 * HID);
        const int  n   = pok ? ((p & 3) * HID + (p >> 2)) : 0;
#pragma unroll
        for (int mi = 0; mi < 3; ++mi) {
#pragma unroll
            for (int kt = 0; kt < 2; ++kt) {
                f16x8 f;
#pragma unroll
                for (int j = 0; j < 8; ++j) {
                    const int k = kt * 32 + qq * 8 + j;
                    const float v = (pok && k < HID) ? mats[mi][n * HID + k] : 0.0f;
                    f[j] = (_Float16)v;
                }
                wa[mi][tt][kt] = f;
            }
        }
        // C-row constants: rows of this lane are p_r = T*16 + qq*4 + r
#pragma unroll
        for (int r = 0; r < 4; ++r) {
            const int  pr = T * 16 + qq * 4 + r;
            const bool ok = (tt < nt) && (pr < 4 * HID);
            const int  nr = ok ? ((pr & 3) * HID + (pr >> 2)) : 0;
            wxC[tt][r] = ok ? w_ih0[nr] : 0.0f;
            bAC[tt][r] = ok ? (b_ih0[nr] + b_hh0[nr]) : 0.0f;
            bBC[tt][r] = ok ? (b_ih1[nr] + b_hh1[nr]) : 0.0f;
        }
    }

    // ---- h-write offset per tile: this lane owns unit j = T*4 + qq, batch l15
    int wOff[2];
#pragma unroll
    for (int tt = 0; tt < 2; ++tt) {
        const int j = Ts[tt] * 4 + qq;                    // <= 63 always
        const int chunk = (((j >> 5) * 4) + ((j >> 3) & 3)) * 16 + l15;
        wOff[tt] = chunk * 8 + (j & 7);                   // half-index
    }

    float c1[2] = {0.f, 0.f};
    float c2[2] = {0.f, 0.f};
    int cur = 0;

    __syncthreads();   // xs + h zeros visible

    for (int t = 0; t < SEQ; ++t) {
        const f16x8* h1c = h1f[cur];
        const f16x8* h2c = h2f[cur];
        f16x8* h1n = h1f[cur ^ 1];
        f16x8* h2n = h2f[cur ^ 1];

        // B-fragments of h1[t-1], h2[t-1] (shared by all my tiles) + x
        const f16x8 hb0 = h1c[qq * 16 + l15];
        const f16x8 hb1 = h1c[64 + qq * 16 + l15];
        const f16x8 sb0 = h2c[qq * 16 + l15];       // prefetched for L2
        const f16x8 sb1 = h2c[64 + qq * 16 + l15];
        const float xv  = xs[l15 * XP + t];

        // ============ Layer 1: acc = W_hh0 @ h1 + wx*x + bias, in-reg cell ==
        _Float16 h1w[2];
#pragma unroll
        for (int tt = 0; tt < 2; ++tt) {
            if (tt < nt) {
                f32x4 acc;
#pragma unroll
                for (int r = 0; r < 4; ++r) acc[r] = wxC[tt][r] * xv + bAC[tt][r];
                acc = __builtin_amdgcn_mfma_f32_16x16x32_f16(wa[0][tt][0], hb0, acc, 0, 0, 0);
                acc = __builtin_amdgcn_mfma_f32_16x16x32_f16(wa[0][tt][1], hb1, acc, 0, 0, 0);
                h1w[tt] = (_Float16)lstm_cell(acc, c1[tt]);
            }
        }
#pragma unroll
        for (int tt = 0; tt < 2; ++tt)
            if (tt < nt) ((_Float16*)h1n)[wOff[tt]] = h1w[tt];
        __syncthreads();   // h1[t] visible

        // ============ Layer 2: acc = W_ih1 @ h1[t] + W_hh1 @ h2[t-1] + bias =
        const f16x8 pb0 = h1n[qq * 16 + l15];
        const f16x8 pb1 = h1n[64 + qq * 16 + l15];
        _Float16 h2w[2];
#pragma unroll
        for (int tt = 0; tt < 2; ++tt) {
            if (tt < nt) {
                f32x4 acc;
#pragma unroll
                for (int r = 0; r < 4; ++r) acc[r] = bBC[tt][r];
                acc = __builtin_amdgcn_mfma_f32_16x16x32_f16(wa[1][tt][0], pb0, acc, 0, 0, 0);
                acc = __builtin_amdgcn_mfma_f32_16x16x32_f16(wa[1][tt][1], pb1, acc, 0, 0, 0);
                acc = __builtin_amdgcn_mfma_f32_16x16x32_f16(wa[2][tt][0], sb0, acc, 0, 0, 0);
                acc = __builtin_amdgcn_mfma_f32_16x16x32_f16(wa[2][tt][1], sb1, acc, 0, 0, 0);
                h2w[tt] = (_Float16)lstm_cell(acc, c2[tt]);
            }
        }
#pragma unroll
        for (int tt = 0; tt < 2; ++tt)
            if (tt < nt) ((_Float16*)h2n)[wOff[tt]] = h2w[tt];
        __syncthreads();   // h2[t] visible
        cur ^= 1;
    }

    // ============ FC head: out[b] = h2[T-1] . fc_w + fc_b ============
    if (tid < NB) {
        const int m = tid;
        const _Float16* h2e = (const _Float16*)h2f[cur];
        float s = fc_b[0];
        for (int j = 0; j < HID; ++j) {
            const int chunk = (((j >> 5) * 4) + ((j >> 3) & 3)) * 16 + m;
            s += fc_w[j] * (float)h2e[chunk * 8 + (j & 7)];
        }
        out[b0 + m] = s;
    }
}

extern "C" void kernel_launch(void* const* d_in, const int* in_sizes, int n_in,
                              void* d_out, int out_size, void* d_ws, size_t ws_size,
                              hipStream_t stream) {
    const float* x     = (const float*)d_in[0];
    const float* w_ih0 = (const float*)d_in[1];
    const float* w_hh0 = (const float*)d_in[2];
    const float* b_ih0 = (const float*)d_in[3];
    const float* b_hh0 = (const float*)d_in[4];
    const float* w_ih1 = (const float*)d_in[5];
    const float* w_hh1 = (const float*)d_in[6];
    const float* b_ih1 = (const float*)d_in[7];
    const float* b_hh1 = (const float*)d_in[8];
    const float* fc_w  = (const float*)d_in[9];
    const float* fc_b  = (const float*)d_in[10];
    float* out = (float*)d_out;

    const int B = in_sizes[0] / SEQ;  // 4096

    lstm2_fc_tmfma<<<B / NB, NTHREADS, 0, stream>>>(
        x, w_ih0, w_hh0, b_ih0, b_hh0, w_ih1, w_hh1, b_ih1, b_hh1, fc_w, fc_b, out);
}

// Round 6
// 799.050 us; speedup vs baseline: 4.8338x; 1.0913x over previous
//
#include <hip/hip_runtime.h>

// 2-layer LSTM (H=50) + FC head. Transposed-MFMA fp16, cross-layer pipelined.
// gates^T[200][16] = W @ h^T : A = weights (register-resident), B = h (LDS
// fragment layout). Gate rows permuted p = 4*j + g so one lane holds all 4
// gates of unit j = w*4+qq, batch l15 -> cell update fully in-register.
// PIPELINE: phase p computes L1[p] and L2[p-1]; both read h1[p-1] (shared
// fragments) and h2[p-2] -> ONE barrier per phase (was 2), 513 phases.
// 13 p-tiles over 13 waves (832 threads): perfectly balanced, 1 tile/wave.
// B=4096, T=512. Grid = 256 blocks; NB=16 batch/block.

#define HID 50
#define SEQ 512
#define NB 16
#define NTHREADS 832      // 13 waves = 13 tiles
#define XP 516            // xs row stride (floats)

typedef _Float16 f16x8 __attribute__((ext_vector_type(8)));
typedef float    f32x4 __attribute__((ext_vector_type(4)));

__device__ __forceinline__ float sigf(float x) {
    return 1.0f / (1.0f + __expf(-x));
}
__device__ __forceinline__ float tanh_fast(float x) {
    return 2.0f / (1.0f + __expf(-2.0f * x)) - 1.0f;  // saturates correctly
}
__device__ __forceinline__ float lstm_cell(const f32x4 g, float& c) {
    const float ii = sigf(g[0]);
    const float ff = sigf(g[1]);
    const float gg = tanh_fast(g[2]);
    const float oo = sigf(g[3]);
    c = ff * c + ii * gg;
    return oo * tanh_fast(c);
}

// h LDS layout: 16B chunk (kt*4+qh)*16 + m holds h[m][k = kt*32+qh*8+0..7].
// B-frag reader (lane m=l15, quad qq, k-chunk kt) reads chunk (kt*4+qq)*16+m:
// 64 lanes -> 64 distinct contiguous chunks, conflict-free ds_read_b128.
// Writer of h[m][j]: chunk ((j>>5)*4+((j>>3)&3))*16 + m, half j&7. Garbage at
// j=50..51 is harmless: A-side weight fragments are zero for k>=50.

__global__ __launch_bounds__(NTHREADS, 1)
void lstm2_fc_pipe(const float* __restrict__ x,
                   const float* __restrict__ w_ih0,
                   const float* __restrict__ w_hh0,
                   const float* __restrict__ b_ih0,
                   const float* __restrict__ b_hh0,
                   const float* __restrict__ w_ih1,
                   const float* __restrict__ w_hh1,
                   const float* __restrict__ b_ih1,
                   const float* __restrict__ b_hh1,
                   const float* __restrict__ fc_w,
                   const float* __restrict__ fc_b,
                   float* __restrict__ out)
{
    __shared__ float xs[NB * XP];        // 33 KB  x for all 512 steps
    __shared__ f16x8 h1f[2][128];        //  4 KB  h1 double-buffered, frag layout
    __shared__ f16x8 h2f[2][128];        //  4 KB  h2 double-buffered

    const int tid = threadIdx.x;
    const int b0  = blockIdx.x * NB;
    const int w   = tid >> 6;            // wave id 0..12 == p-tile id
    const int l15 = tid & 15;            // MFMA lane column (batch m / A-row)
    const int qq  = (tid >> 4) & 3;      // MFMA lane quad

    // ---- stage x into LDS (coalesced float4) ----
    for (int idx = tid; idx < NB * 128; idx += NTHREADS) {
        const int b  = idx >> 7;
        const int t4 = idx & 127;
        *(float4*)&xs[b * XP + t4 * 4] =
            *(const float4*)&x[(size_t)(b0 + b) * SEQ + t4 * 4];
    }
    // ---- zero h buffers (padding k=52..63 must stay zero forever) ----
    if (tid < 256) {
        f16x8 z = {};
        h1f[tid >> 7][tid & 127] = z;
        h2f[tid >> 7][tid & 127] = z;
    }

    // ---- load weight A-fragments (one-time), gate rows permuted ----
    // A-frag: lane holds W[p = w*16 + l15][k = kt*32 + qq*8 + j], source gate
    // row n(p) = (p&3)*HID + (p>>2). Zero outside p<200 / k<50.
    const float* mats[3] = { w_hh0, w_ih1, w_hh1 };
    f16x8 wa[3][2];                      // [mat][kt] = 6 frags = 24 VGPR
    {
        const int  pA  = w * 16 + l15;
        const bool pok = (pA < 4 * HID);
        const int  n   = pok ? ((pA & 3) * HID + (pA >> 2)) : 0;
#pragma unroll
        for (int mi = 0; mi < 3; ++mi) {
#pragma unroll
            for (int kt = 0; kt < 2; ++kt) {
                f16x8 f;
#pragma unroll
                for (int j = 0; j < 8; ++j) {
                    const int k = kt * 32 + qq * 8 + j;
                    const float v = (pok && k < HID) ? mats[mi][n * HID + k] : 0.0f;
                    f[j] = (_Float16)v;
                }
                wa[mi][kt] = f;
            }
        }
    }
    // C-row constants: this lane's 4 C-regs are rows p_r = w*16 + qq*4 + r,
    // i.e. gates r of unit j = w*4 + qq.
    float wxC[4], bAC[4], bBC[4];
#pragma unroll
    for (int r = 0; r < 4; ++r) {
        const int  pr = w * 16 + qq * 4 + r;
        const bool ok = (pr < 4 * HID);
        const int  nr = ok ? ((pr & 3) * HID + (pr >> 2)) : 0;
        wxC[r] = ok ? w_ih0[nr] : 0.0f;
        bAC[r] = ok ? (b_ih0[nr] + b_hh0[nr]) : 0.0f;
        bBC[r] = ok ? (b_ih1[nr] + b_hh1[nr]) : 0.0f;
    }

    // ---- h-write offset: this lane owns unit j = w*4 + qq, batch l15 ----
    const int ju    = w * 4 + qq;                      // <= 51
    const int wOff  = ((((ju >> 5) * 4) + ((ju >> 3) & 3)) * 16 + l15) * 8 + (ju & 7);

    float c1 = 0.f, c2 = 0.f;
    int cur = 0;

    __syncthreads();   // xs + h zeros visible

    // ---- 513 phases: phase p = L1 step p  +  L2 step p-1 ----
    for (int p = 0; p <= SEQ; ++p) {
        const f16x8* h1o = h1f[cur];         // h1[p-1]
        const f16x8* h2o = h2f[cur];         // h2[p-2]
        f16x8* h1n = h1f[cur ^ 1];           // h1[p]
        f16x8* h2n = h2f[cur ^ 1];           // h2[p-1]

        const f16x8 hb0 = h1o[qq * 16 + l15];        // shared by L1 and L2
        const f16x8 hb1 = h1o[64 + qq * 16 + l15];

        if (p < SEQ) {
            // L1 step p: acc = W_hh0 @ h1[p-1] + wx*x[p] + bias
            const float xv = xs[l15 * XP + p];
            f32x4 acc;
#pragma unroll
            for (int r = 0; r < 4; ++r) acc[r] = wxC[r] * xv + bAC[r];
            acc = __builtin_amdgcn_mfma_f32_16x16x32_f16(wa[0][0], hb0, acc, 0, 0, 0);
            acc = __builtin_amdgcn_mfma_f32_16x16x32_f16(wa[0][1], hb1, acc, 0, 0, 0);
            ((_Float16*)h1n)[wOff] = (_Float16)lstm_cell(acc, c1);
        }
        if (p > 0) {
            // L2 step p-1: acc = W_ih1 @ h1[p-1] + W_hh1 @ h2[p-2] + bias
            const f16x8 sb0 = h2o[qq * 16 + l15];
            const f16x8 sb1 = h2o[64 + qq * 16 + l15];
            f32x4 acc;
#pragma unroll
            for (int r = 0; r < 4; ++r) acc[r] = bBC[r];
            acc = __builtin_amdgcn_mfma_f32_16x16x32_f16(wa[1][0], hb0, acc, 0, 0, 0);
            acc = __builtin_amdgcn_mfma_f32_16x16x32_f16(wa[1][1], hb1, acc, 0, 0, 0);
            acc = __builtin_amdgcn_mfma_f32_16x16x32_f16(wa[2][0], sb0, acc, 0, 0, 0);
            acc = __builtin_amdgcn_mfma_f32_16x16x32_f16(wa[2][1], sb1, acc, 0, 0, 0);
            ((_Float16*)h2n)[wOff] = (_Float16)lstm_cell(acc, c2);
        }
        __syncthreads();   // h1[p], h2[p-1] visible
        cur ^= 1;
    }
    // after 513 phases: cur = 1, h2f[cur] = h2[511]

    // ============ FC head: out[b] = h2[T-1] . fc_w + fc_b ============
    if (tid < NB) {
        const int m = tid;
        const _Float16* h2e = (const _Float16*)h2f[cur];
        float s = fc_b[0];
        for (int j = 0; j < HID; ++j) {
            const int chunk = (((j >> 5) * 4) + ((j >> 3) & 3)) * 16 + m;
            s += fc_w[j] * (float)h2e[chunk * 8 + (j & 7)];
        }
        out[b0 + m] = s;
    }
}

extern "C" void kernel_launch(void* const* d_in, const int* in_sizes, int n_in,
                              void* d_out, int out_size, void* d_ws, size_t ws_size,
                              hipStream_t stream) {
    const float* x     = (const float*)d_in[0];
    const float* w_ih0 = (const float*)d_in[1];
    const float* w_hh0 = (const float*)d_in[2];
    const float* b_ih0 = (const float*)d_in[3];
    const float* b_hh0 = (const float*)d_in[4];
    const float* w_ih1 = (const float*)d_in[5];
    const float* w_hh1 = (const float*)d_in[6];
    const float* b_ih1 = (const float*)d_in[7];
    const float* b_hh1 = (const float*)d_in[8];
    const float* fc_w  = (const float*)d_in[9];
    const float* fc_b  = (const float*)d_in[10];
    float* out = (float*)d_out;

    const int B = in_sizes[0] / SEQ;  // 4096

    lstm2_fc_pipe<<<B / NB, NTHREADS, 0, stream>>>(
        x, w_ih0, w_hh0, b_ih0, b_hh0, w_ih1, w_hh1, b_ih1, b_hh1, fc_w, fc_b, out);
}

// Round 7
// 436.149 us; speedup vs baseline: 8.8557x; 1.8321x over previous
//
#include <hip/hip_runtime.h>

// 2-layer LSTM (H=50) + FC head. Transposed-MFMA fp16, cross-layer pipelined,
// VALU-diet edition.
//  - gates^T = W @ h^T; A = weights (register-resident frags), B = h (LDS).
//  - Gate rows permuted p = 4*j + g: one lane owns all 4 gates of unit
//    j = w*4 + qq, batch l15 -> cell update fully in-register.
//  - Phase p computes L1[p] and L2[p-1]; ONE barrier/phase, 513 phases.
//  - x-term and ALL biases ride the MFMA's dead K-lanes: h1 buffer k=50
//    holds x[m][t], k=51 holds 1.0; L1 A-frag k=50/51 = (w_ih0, biasL1);
//    w_ih1 A-frag k=51 = biasL2. Accumulators init to zero.
//  - Activations are division-free: v_rcp + v_exp2 (native builtins).
// B=4096, T=512. Grid = 256 blocks x 832 threads (13 waves = 13 p-tiles).

#define HID 50
#define SEQ 512
#define NB 16
#define NTHREADS 832
#define XP 516            // xs row stride (floats)

typedef _Float16 f16x8 __attribute__((ext_vector_type(8)));
typedef float    f32x4 __attribute__((ext_vector_type(4)));

#define LOG2E 1.44269504f

__device__ __forceinline__ float sigf(float x) {
    // rcp(1 + 2^(-x*log2e)) : 4 VALU, exact saturation
    return __builtin_amdgcn_rcpf(1.0f + __builtin_amdgcn_exp2f(x * -LOG2E));
}
__device__ __forceinline__ float tanh_fast(float x) {
    // 1 - 2*rcp(1 + 2^(2x*log2e)) : 5 VALU, exact saturation
    return 1.0f - 2.0f * __builtin_amdgcn_rcpf(
        1.0f + __builtin_amdgcn_exp2f(x * (2.0f * LOG2E)));
}
__device__ __forceinline__ float lstm_cell(const f32x4 g, float& c) {
    const float ii = sigf(g[0]);
    const float ff = sigf(g[1]);
    const float gg = tanh_fast(g[2]);
    const float oo = sigf(g[3]);
    c = ff * c + ii * gg;
    return oo * tanh_fast(c);
}

// h LDS layout: 16B chunk (kt*4+qh)*16 + m holds h[m][k = kt*32+qh*8+0..7].
// B-frag reader (lane m=l15, quad qq, k-chunk kt) reads chunk (kt*4+qq)*16+m:
// 64 lanes -> 64 distinct contiguous chunks, conflict-free ds_read_b128.
// Writer of h[m][j]: chunk ((j>>5)*4+((j>>3)&3))*16 + m, half j&7.
// j=50 chunk 96+m half 2 (holds x), j=51 chunk 96+m half 3 (holds 1.0).

__global__ __launch_bounds__(NTHREADS, 1)
void lstm2_fc_diet(const float* __restrict__ x,
                   const float* __restrict__ w_ih0,
                   const float* __restrict__ w_hh0,
                   const float* __restrict__ b_ih0,
                   const float* __restrict__ b_hh0,
                   const float* __restrict__ w_ih1,
                   const float* __restrict__ w_hh1,
                   const float* __restrict__ b_ih1,
                   const float* __restrict__ b_hh1,
                   const float* __restrict__ fc_w,
                   const float* __restrict__ fc_b,
                   float* __restrict__ out)
{
    __shared__ float xs[NB * XP];        // 33 KB  x for all 512 steps
    __shared__ f16x8 h1f[2][128];        //  4 KB  h1 double-buffered, frag layout
    __shared__ f16x8 h2f[2][128];        //  4 KB  h2 double-buffered

    const int tid = threadIdx.x;
    const int b0  = blockIdx.x * NB;
    const int w   = tid >> 6;            // wave id 0..12 == p-tile id
    const int l15 = tid & 15;            // MFMA lane column (batch m / A-row)
    const int qq  = (tid >> 4) & 3;      // MFMA lane quad

    // ---- stage x into LDS (coalesced float4) ----
    for (int idx = tid; idx < NB * 128; idx += NTHREADS) {
        const int b  = idx >> 7;
        const int t4 = idx & 127;
        *(float4*)&xs[b * XP + t4 * 4] =
            *(const float4*)&x[(size_t)(b0 + b) * SEQ + t4 * 4];
    }
    // zero the x[512..515] pad column (read at the last x-prefetch)
    if (tid < NB) {
        const float4 z = {0.f, 0.f, 0.f, 0.f};
        *(float4*)&xs[tid * XP + 512] = z;
    }
    // ---- zero h buffers (padding k must stay controlled) ----
    if (tid < 256) {
        f16x8 z = {};
        h1f[tid >> 7][tid & 127] = z;
        h2f[tid >> 7][tid & 127] = z;
    }

    // ---- load weight A-fragments (one-time), gate rows permuted ----
    // A-frag: lane holds W[p = w*16 + l15][k = kt*32 + qq*8 + j], source gate
    // row n(p) = (p&3)*HID + (p>>2). Specials: mat0 k=50 -> w_ih0, k=51 ->
    // biasL1; mat1 k=51 -> biasL2. Zero elsewhere outside k<50 / p<200.
    const float* mats[3] = { w_hh0, w_ih1, w_hh1 };
    f16x8 wa[3][2];                      // [mat][kt] = 6 frags = 24 VGPR
    {
        const int  pA  = w * 16 + l15;
        const bool pok = (pA < 4 * HID);
        const int  n   = pok ? ((pA & 3) * HID + (pA >> 2)) : 0;
#pragma unroll
        for (int mi = 0; mi < 3; ++mi) {
#pragma unroll
            for (int kt = 0; kt < 2; ++kt) {
                f16x8 f;
#pragma unroll
                for (int j = 0; j < 8; ++j) {
                    const int k = kt * 32 + qq * 8 + j;
                    float v = 0.0f;
                    if (pok) {
                        if (k < HID)                     v = mats[mi][n * HID + k];
                        else if (mi == 0 && k == HID)    v = w_ih0[n];
                        else if (mi == 0 && k == HID+1)  v = b_ih0[n] + b_hh0[n];
                        else if (mi == 1 && k == HID+1)  v = b_ih1[n] + b_hh1[n];
                    }
                    f[j] = (_Float16)v;
                }
                wa[mi][kt] = f;
            }
        }
    }

    // ---- h-write offset: this lane owns unit j = w*4 + qq, batch l15 ----
    const int ju   = w * 4 + qq;                       // <= 51
    const int wOff = ((((ju >> 5) * 4) + ((ju >> 3) & 3)) * 16 + l15) * 8 + (ju & 7);
    const bool isXlane = (ju == HID);                  // writes x into h1 k=50
    const bool isOne   = (ju == HID + 1);              // writes 1.0 into k=51

    float c1 = 0.f, c2 = 0.f;
    int cur = 0;

    __syncthreads();   // xs + zeros visible

    // ---- seed h1f[0] specials: k=50 = x[m][0], k=51 = 1.0 ----
    if (tid < NB) {
        _Float16* e0 = (_Float16*)&h1f[0][96 + tid];
        e0[2] = (_Float16)x[(size_t)(b0 + tid) * SEQ];
        e0[3] = (_Float16)1.0f;
    }
    __syncthreads();

    // ---- 513 phases: phase p = L1 step p  +  L2 step p-1 ----
#pragma unroll 2
    for (int p = 0; p <= SEQ; ++p) {
        const f16x8* h1o = h1f[cur];         // h1[p-1] (+ x[p], 1.0 in k=50/51)
        const f16x8* h2o = h2f[cur];         // h2[p-2]
        f16x8* h1n = h1f[cur ^ 1];           // h1[p]
        f16x8* h2n = h2f[cur ^ 1];           // h2[p-1]

        const f16x8 hb0 = h1o[qq * 16 + l15];        // shared by L1 and L2
        const f16x8 hb1 = h1o[64 + qq * 16 + l15];

        if (p < SEQ) {
            // L1 step p: gates = W_hh0 @ h1[p-1] + w_ih0*x[p] + biasL1 (all in MFMA)
            f32x4 acc = {0.f, 0.f, 0.f, 0.f};
            acc = __builtin_amdgcn_mfma_f32_16x16x32_f16(wa[0][0], hb0, acc, 0, 0, 0);
            acc = __builtin_amdgcn_mfma_f32_16x16x32_f16(wa[0][1], hb1, acc, 0, 0, 0);
            _Float16 hw = (_Float16)lstm_cell(acc, c1);
            if (isXlane) hw = (_Float16)xs[l15 * XP + (p + 1)];  // x for phase p+1
            if (isOne)   hw = (_Float16)1.0f;
            ((_Float16*)h1n)[wOff] = hw;
        }
        if (p > 0) {
            // L2 step p-1: gates = W_ih1 @ h1[p-1] + W_hh1 @ h2[p-2] + biasL2
            const f16x8 sb0 = h2o[qq * 16 + l15];
            const f16x8 sb1 = h2o[64 + qq * 16 + l15];
            f32x4 acc = {0.f, 0.f, 0.f, 0.f};
            acc = __builtin_amdgcn_mfma_f32_16x16x32_f16(wa[1][0], hb0, acc, 0, 0, 0);
            acc = __builtin_amdgcn_mfma_f32_16x16x32_f16(wa[1][1], hb1, acc, 0, 0, 0);
            acc = __builtin_amdgcn_mfma_f32_16x16x32_f16(wa[2][0], sb0, acc, 0, 0, 0);
            acc = __builtin_amdgcn_mfma_f32_16x16x32_f16(wa[2][1], sb1, acc, 0, 0, 0);
            ((_Float16*)h2n)[wOff] = (_Float16)lstm_cell(acc, c2);
        }
        __syncthreads();   // h1[p], h2[p-1] visible
        cur ^= 1;
    }
    // after 513 phases: cur = 1, h2f[cur] = h2[511]

    // ============ FC head: out[b] = h2[T-1] . fc_w + fc_b ============
    if (tid < NB) {
        const int m = tid;
        const _Float16* h2e = (const _Float16*)h2f[cur];
        float s = fc_b[0];
        for (int j = 0; j < HID; ++j) {
            const int chunk = (((j >> 5) * 4) + ((j >> 3) & 3)) * 16 + m;
            s += fc_w[j] * (float)h2e[chunk * 8 + (j & 7)];
        }
        out[b0 + m] = s;
    }
}

extern "C" void kernel_launch(void* const* d_in, const int* in_sizes, int n_in,
                              void* d_out, int out_size, void* d_ws, size_t ws_size,
                              hipStream_t stream) {
    const float* x     = (const float*)d_in[0];
    const float* w_ih0 = (const float*)d_in[1];
    const float* w_hh0 = (const float*)d_in[2];
    const float* b_ih0 = (const float*)d_in[3];
    const float* b_hh0 = (const float*)d_in[4];
    const float* w_ih1 = (const float*)d_in[5];
    const float* w_hh1 = (const float*)d_in[6];
    const float* b_ih1 = (const float*)d_in[7];
    const float* b_hh1 = (const float*)d_in[8];
    const float* fc_w  = (const float*)d_in[9];
    const float* fc_b  = (const float*)d_in[10];
    float* out = (float*)d_out;

    const int B = in_sizes[0] / SEQ;  // 4096

    lstm2_fc_diet<<<B / NB, NTHREADS, 0, stream>>>(
        x, w_ih0, w_hh0, b_ih0, b_hh0, w_ih1, w_hh1, b_ih1, b_hh1, fc_w, fc_b, out);
}